// Round 17
// baseline (268.649 us; speedup 1.0000x reference)
//
#include <hip/hip_runtime.h>
#include <hip/hip_fp16.h>

#define D 128
#define FFN 512
#define BOT 64
#define EPB 4096      // edges per bucketing block

typedef _Float16 f16x8 __attribute__((ext_vector_type(8)));
typedef float f32x4 __attribute__((ext_vector_type(4)));

// ================ CSR build via bucketed counting sort ================

__global__ __launch_bounds__(256) void k_bcnt(const int* __restrict__ dst, int* __restrict__ bcnt, int nE) {
  __shared__ int h[256];
  int t = threadIdx.x;
  h[t] = 0;
  __syncthreads();
  int base = blockIdx.x * EPB;
  #pragma unroll
  for (int m = 0; m < EPB / 256; ++m) {
    int idx = base + m * 256 + t;
    if (idx < nE) atomicAdd(&h[dst[idx] >> 8], 1);
  }
  __syncthreads();
  if (h[t] > 0) atomicAdd(&bcnt[t], h[t]);
}

__global__ __launch_bounds__(256) void k_bscan(const int* __restrict__ bcnt, int* __restrict__ boff,
                                               int* __restrict__ bcur, int nbkt, int nE) {
  __shared__ int s[256];
  int t = threadIdx.x;
  int v = (t < nbkt) ? bcnt[t] : 0;
  s[t] = v;
  __syncthreads();
  for (int d = 1; d < 256; d <<= 1) {
    int add = (t >= d) ? s[t - d] : 0;
    __syncthreads();
    s[t] += add;
    __syncthreads();
  }
  int ex = s[t] - v;
  boff[t] = ex;
  bcur[t] = ex;
  if (t == 255) boff[256] = nE;
  if (t >= nbkt) boff[t] = nE;
}

__global__ __launch_bounds__(256) void k_bscatter(const int* __restrict__ ei, int* __restrict__ bcur,
                                                  uint2* __restrict__ bed, int nE) {
  __shared__ uint2 st[EPB];
  __shared__ int cnt[256], off[256], base[256], cur[256];
  int t = threadIdx.x;
  int blk0 = blockIdx.x * EPB;
  int nblk = nE - blk0;
  if (nblk > EPB) nblk = EPB;

  cnt[t] = 0;
  cur[t] = 0;
  __syncthreads();

  int rs[EPB / 256], rd[EPB / 256];
  #pragma unroll
  for (int m = 0; m < EPB / 256; ++m) {
    int idx = blk0 + m * 256 + t;
    if (idx < nE) {
      rs[m] = ei[idx];
      rd[m] = ei[nE + idx];
      atomicAdd(&cnt[rd[m] >> 8], 1);
    } else {
      rd[m] = -1;
    }
  }
  __syncthreads();

  int v = cnt[t];
  off[t] = v;
  __syncthreads();
  for (int d = 1; d < 256; d <<= 1) {
    int add = (t >= d) ? off[t - d] : 0;
    __syncthreads();
    off[t] += add;
    __syncthreads();
  }
  int ex = off[t] - v;
  __syncthreads();
  off[t] = ex;
  base[t] = (v > 0) ? atomicAdd(&bcur[t], v) : 0;
  __syncthreads();

  #pragma unroll
  for (int m = 0; m < EPB / 256; ++m) {
    if (rd[m] >= 0) {
      int b = rd[m] >> 8;
      int p = off[b] + atomicAdd(&cur[b], 1);
      st[p] = make_uint2((unsigned)rs[m], (unsigned)rd[m]);
    }
  }
  __syncthreads();

  for (int j = t; j < nblk; j += 256) {
    uint2 pr = st[j];
    int b = (int)(pr.y >> 8);
    bed[base[b] + (j - off[b])] = pr;
  }
}

__global__ __launch_bounds__(256) void k_bcsr(const uint2* __restrict__ bed, const int* __restrict__ boff,
                                              int* __restrict__ rowptr, float* __restrict__ nrm,
                                              int* __restrict__ col, int N, int nE) {
  __shared__ int cnt[256], noff[256], cur[256];
  int t = threadIdx.x;
  int b = blockIdx.x;
  int e0 = boff[b], e1 = boff[b + 1];

  cnt[t] = 0;
  __syncthreads();
  for (int j = e0 + t; j < e1; j += 256)
    atomicAdd(&cnt[bed[j].y & 255], 1);
  __syncthreads();

  int v = cnt[t];
  noff[t] = v;
  __syncthreads();
  for (int d = 1; d < 256; d <<= 1) {
    int add = (t >= d) ? noff[t - d] : 0;
    __syncthreads();
    noff[t] += add;
    __syncthreads();
  }
  int ex = noff[t] - v;
  __syncthreads();
  noff[t] = ex;
  cur[t] = ex;
  __syncthreads();

  int node = (b << 8) + t;
  if (node < N) {
    rowptr[node] = e0 + ex;
    nrm[node] = rsqrtf((float)v + 1.0f);
  }
  if (b == 0 && t == 0) rowptr[N] = nE;

  for (int j = e0 + t; j < e1; j += 256) {
    uint2 pr = bed[j];
    int d2 = (int)(pr.y & 255);
    int p = atomicAdd(&cur[d2], 1);
    col[e0 + p] = (int)pr.x;
  }
}

// ---------------- split helpers ----------------

__global__ __launch_bounds__(256) void k_split(const float* __restrict__ X,
                                               __half* __restrict__ Xh, __half* __restrict__ Xl, int n8) {
  int i = blockIdx.x * 256 + threadIdx.x;
  if (i >= n8) return;
  float4 a = ((const float4*)X)[i * 2];
  float4 b = ((const float4*)X)[i * 2 + 1];
  float v[8] = {a.x, a.y, a.z, a.w, b.x, b.y, b.z, b.w};
  __half2 hh[4], ll[4];
  #pragma unroll
  for (int q = 0; q < 4; ++q) {
    __half h0 = __float2half_rn(v[2 * q]);
    __half h1 = __float2half_rn(v[2 * q + 1]);
    __half l0 = __float2half_rn(v[2 * q] - __half2float(h0));
    __half l1 = __float2half_rn(v[2 * q + 1] - __half2float(h1));
    hh[q] = __halves2half2(h0, h1);
    ll[q] = __halves2half2(l0, l1);
  }
  *(uint4*)(Xh + (size_t)i * 8) = *(uint4*)hh;
  *(uint4*)(Xl + (size_t)i * 8) = *(uint4*)ll;
}

__global__ __launch_bounds__(256) void k_splitw(const float* __restrict__ W,
                                                __half* __restrict__ WhT, __half* __restrict__ WlT,
                                                int K, int N) {
  int id = blockIdx.x * 256 + threadIdx.x;
  if (id >= K * N) return;
  int n = id / K, k = id % K;
  float v = W[(size_t)k * N + n];
  __half h = __float2half_rn(v);
  WhT[id] = h;
  WlT[id] = __float2half_rn(v - __half2float(h));
}

__global__ __launch_bounds__(256) void k_splitwc(const float* __restrict__ W,
                                                 __half* __restrict__ WhT, __half* __restrict__ WlT,
                                                 int total) {
  int id = blockIdx.x * 256 + threadIdx.x;
  if (id >= total) return;
  int l = id / (D * D), r = id % (D * D);
  int n = r / D, k = r % D;
  float v = W[(size_t)l * D * D + (size_t)k * D + n];
  __half h = __float2half_rn(v);
  WhT[id] = h;
  WlT[id] = __float2half_rn(v - __half2float(h));
}

// ---------------- conv GEMM v3: Y = (X @ W) * nrm[row] ----------------
// X fragments (h+l) gathered ONCE into registers; full W (h+l) staged into
// LDS once (69.6 KB, coalesced); ONE barrier. 4 waves: 2m x 2n; tile 32 x 64.

__global__ __launch_bounds__(256, 2)
void k_conv(const __half* __restrict__ Xh_g, const __half* __restrict__ Xl_g,
            const __half* __restrict__ WhT, const __half* __restrict__ WlT,
            const float* __restrict__ aux, __half* __restrict__ Yo, int M) {
  __shared__ __half Bhs[128][136], Bls[128][136];

  const int t = threadIdx.x;
  const int rbase = blockIdx.x * 64;
  const int lane = t & 63, wid = t >> 6;
  const int wr = (wid >> 1) * 32;
  const int wc = (wid & 1) * 64;
  const int lr = lane & 15, lq = lane >> 4;

  // stage whole W (128 cols x 128 k), h+l
  #pragma unroll
  for (int mm = 0; mm < 8; ++mm) {
    int idx = mm * 256 + t;
    int c = idx >> 4, q = idx & 15;
    size_t src = (size_t)c * D + q * 8;
    *(uint4*)&Bhs[c][q * 8] = *(const uint4*)(WhT + src);
    *(uint4*)&Bls[c][q * 8] = *(const uint4*)(WlT + src);
  }

  // gather X fragments into registers (one time)
  f16x8 fa[2][4], fal[2][4];
  #pragma unroll
  for (int m = 0; m < 2; ++m) {
    int row = rbase + wr + m * 16 + lr;
    bool ok = row < M;
    #pragma unroll
    for (int kf = 0; kf < 4; ++kf) {
      uint4 vh = {0, 0, 0, 0}, vl = {0, 0, 0, 0};
      if (ok) {
        vh = *(const uint4*)(Xh_g + (size_t)row * D + kf * 32 + lq * 8);
        vl = *(const uint4*)(Xl_g + (size_t)row * D + kf * 32 + lq * 8);
      }
      fa[m][kf] = *(f16x8*)&vh;
      fal[m][kf] = *(f16x8*)&vl;
    }
  }
  __syncthreads();

  f32x4 acc[2][4];
  #pragma unroll
  for (int m = 0; m < 2; ++m)
    #pragma unroll
    for (int n = 0; n < 4; ++n) acc[m][n] = (f32x4){0.f, 0.f, 0.f, 0.f};

  #pragma unroll
  for (int kf = 0; kf < 4; ++kf) {
    f16x8 fb[4], fbl[4];
    #pragma unroll
    for (int n = 0; n < 4; ++n) {
      fb[n]  = *(const f16x8*)&Bhs[wc + n * 16 + lr][kf * 32 + lq * 8];
      fbl[n] = *(const f16x8*)&Bls[wc + n * 16 + lr][kf * 32 + lq * 8];
    }
    #pragma unroll
    for (int m = 0; m < 2; ++m)
      #pragma unroll
      for (int n = 0; n < 4; ++n) {
        acc[m][n] = __builtin_amdgcn_mfma_f32_16x16x32_f16(fa[m][kf], fb[n], acc[m][n], 0, 0, 0);
        acc[m][n] = __builtin_amdgcn_mfma_f32_16x16x32_f16(fa[m][kf], fbl[n], acc[m][n], 0, 0, 0);
        acc[m][n] = __builtin_amdgcn_mfma_f32_16x16x32_f16(fal[m][kf], fb[n], acc[m][n], 0, 0, 0);
      }
  }

  #pragma unroll
  for (int m = 0; m < 2; ++m)
    #pragma unroll
    for (int j = 0; j < 4; ++j) {
      int row = rbase + wr + m * 16 + lq * 4 + j;
      if (row < M) {
        float s = aux[row];
        #pragma unroll
        for (int n = 0; n < 4; ++n) {
          int colg = wc + n * 16 + lr;
          Yo[(size_t)row * D + colg] = __float2half_rn(acc[m][n][j] * s);
        }
      }
    }
}

// ---------------- fused MLP v9: Out = relu(X@W1+b1)@W2 + b2 ----------------
// v2 barrier structure, BM=128: 4 waves each own 32 rows x full 64-col chunk.
// W-staging per chunk amortized over 2x rows; fc1 = 96 MFMAs/wave per chunk.
// LDS = X 69.6K + Ws 34.8K + Hs 18.4K = 122.8 KB -> 1 block/CU (8 waves).

__global__ __launch_bounds__(256, 1)
void k_mlp(const __half* __restrict__ Xh_g, const __half* __restrict__ Xl_g,
           const __half* __restrict__ W1hT, const __half* __restrict__ W1lT,
           const float* __restrict__ B1,
           const __half* __restrict__ W2hT, const __half* __restrict__ W2lT,
           const float* __restrict__ B2,
           float* __restrict__ Out, int M) {
  __shared__ __half Xhs[128][136], Xls[128][136];
  __shared__ __half Ws[2][64][136];     // W1 h/l chunk; reused for W2 h/l
  __shared__ __half Hs[128][72];

  const int t = threadIdx.x;
  const int rbase = blockIdx.x * 128;
  const int lane = t & 63, wid = t >> 6;
  const int wr = wid * 32;              // 4 waves stacked in m
  const int lr = lane & 15, lq = lane >> 4;

  // stage X once, full K (128 rows x 128 k, h+l)
  #pragma unroll
  for (int mm = 0; mm < 8; ++mm) {
    int idx = mm * 256 + t;
    int row = idx >> 4, q = idx & 15;
    int gr = rbase + row;
    uint4 vh = {0, 0, 0, 0}, vl = {0, 0, 0, 0};
    if (gr < M) {
      vh = *(const uint4*)(Xh_g + (size_t)gr * D + q * 8);
      vl = *(const uint4*)(Xl_g + (size_t)gr * D + q * 8);
    }
    *(uint4*)&Xhs[row][q * 8] = vh;
    *(uint4*)&Xls[row][q * 8] = vl;
  }

  f32x4 accO[2][4];
  #pragma unroll
  for (int m = 0; m < 2; ++m)
    #pragma unroll
    for (int n = 0; n < 4; ++n) accO[m][n] = (f32x4){0.f, 0.f, 0.f, 0.f};

  for (int ch = 0; ch < FFN / 64; ++ch) {
    __syncthreads();   // (a) prior fc2 done with Ws/Hs; first iter: X visible
    // stage W1 chunk: 64 ffn-cols x 128 k
    #pragma unroll
    for (int mm = 0; mm < 4; ++mm) {
      int idx = mm * 256 + t;
      int c = idx >> 4, q = idx & 15;
      size_t src = (size_t)(ch * 64 + c) * D + q * 8;
      *(uint4*)&Ws[0][c][q * 8] = *(const uint4*)(W1hT + src);
      *(uint4*)&Ws[1][c][q * 8] = *(const uint4*)(W1lT + src);
    }
    __syncthreads();   // (b) W1 ready

    // ---- fc1: 96 MFMAs/wave, no barrier ----
    f32x4 accH[2][4];
    #pragma unroll
    for (int m = 0; m < 2; ++m)
      #pragma unroll
      for (int n = 0; n < 4; ++n) accH[m][n] = (f32x4){0.f, 0.f, 0.f, 0.f};

    #pragma unroll
    for (int kf = 0; kf < 4; ++kf) {
      f16x8 fa[2], fal[2], fb[4], fbl[4];
      #pragma unroll
      for (int m = 0; m < 2; ++m) {
        fa[m]  = *(const f16x8*)&Xhs[wr + m * 16 + lr][kf * 32 + lq * 8];
        fal[m] = *(const f16x8*)&Xls[wr + m * 16 + lr][kf * 32 + lq * 8];
      }
      #pragma unroll
      for (int n = 0; n < 4; ++n) {
        fb[n]  = *(const f16x8*)&Ws[0][n * 16 + lr][kf * 32 + lq * 8];
        fbl[n] = *(const f16x8*)&Ws[1][n * 16 + lr][kf * 32 + lq * 8];
      }
      #pragma unroll
      for (int m = 0; m < 2; ++m)
        #pragma unroll
        for (int n = 0; n < 4; ++n) {
          accH[m][n] = __builtin_amdgcn_mfma_f32_16x16x32_f16(fa[m], fb[n], accH[m][n], 0, 0, 0);
          accH[m][n] = __builtin_amdgcn_mfma_f32_16x16x32_f16(fa[m], fbl[n], accH[m][n], 0, 0, 0);
          accH[m][n] = __builtin_amdgcn_mfma_f32_16x16x32_f16(fal[m], fb[n], accH[m][n], 0, 0, 0);
        }
    }

    // relu + b1 -> Hs
    {
      float bb1[4];
      #pragma unroll
      for (int n = 0; n < 4; ++n) bb1[n] = B1[ch * 64 + n * 16 + lr];
      #pragma unroll
      for (int m = 0; m < 2; ++m)
        #pragma unroll
        for (int n = 0; n < 4; ++n)
          #pragma unroll
          for (int j = 0; j < 4; ++j) {
            int rl = wr + m * 16 + lq * 4 + j;
            int cl = n * 16 + lr;
            Hs[rl][cl] = __float2half_rn(fmaxf(accH[m][n][j] + bb1[n], 0.f));
          }
    }
    __syncthreads();   // (c) Hs ready; fc1 done reading Ws
    // stage W2 chunk: 64 bot-cols x 64 k into same Ws region
    #pragma unroll
    for (int mm = 0; mm < 2; ++mm) {
      int idx = mm * 256 + t;
      int c = idx >> 3, q = idx & 7;
      size_t src = (size_t)c * FFN + ch * 64 + q * 8;
      *(uint4*)&Ws[0][c][q * 8] = *(const uint4*)(W2hT + src);
      *(uint4*)&Ws[1][c][q * 8] = *(const uint4*)(W2lT + src);
    }
    __syncthreads();   // (d) W2 ready

    // ---- fc2: 32 MFMAs/wave ----
    #pragma unroll
    for (int s = 0; s < 2; ++s) {
      f16x8 fha[2], fwb[4], fwbl[4];
      #pragma unroll
      for (int m = 0; m < 2; ++m)
        fha[m] = *(const f16x8*)&Hs[wr + m * 16 + lr][s * 32 + lq * 8];
      #pragma unroll
      for (int n = 0; n < 4; ++n) {
        fwb[n]  = *(const f16x8*)&Ws[0][n * 16 + lr][s * 32 + lq * 8];
        fwbl[n] = *(const f16x8*)&Ws[1][n * 16 + lr][s * 32 + lq * 8];
      }
      #pragma unroll
      for (int m = 0; m < 2; ++m)
        #pragma unroll
        for (int n = 0; n < 4; ++n) {
          accO[m][n] = __builtin_amdgcn_mfma_f32_16x16x32_f16(fha[m], fwb[n], accO[m][n], 0, 0, 0);
          accO[m][n] = __builtin_amdgcn_mfma_f32_16x16x32_f16(fha[m], fwbl[n], accO[m][n], 0, 0, 0);
        }
    }
  }

  // epilogue: Out += b2
  #pragma unroll
  for (int m = 0; m < 2; ++m)
    #pragma unroll
    for (int j = 0; j < 4; ++j) {
      int row = rbase + wr + m * 16 + lq * 4 + j;
      if (row < M) {
        #pragma unroll
        for (int n = 0; n < 4; ++n) {
          int colg = n * 16 + lr;
          Out[(size_t)row * BOT + colg] = accO[m][n][j] + B2[colg];
        }
      }
    }
}

// ---------------- aggregate: X' = relu(norm[i]*(y_i + sum y_src) + b), split output ----------------
// 16-lane sub-groups, 16B/lane; 8-deep unrolled gather (r15, proven win).

__global__ __launch_bounds__(256) void k_agg(const __half* __restrict__ Y,
                                             const int* __restrict__ rowptr, const int* __restrict__ col,
                                             const float* __restrict__ nrm, const float* __restrict__ bias,
                                             __half* __restrict__ Xh, __half* __restrict__ Xl, int n) {
  int gtid = blockIdx.x * 256 + threadIdx.x;
  int node = gtid >> 4;
  int sl = threadIdx.x & 15;
  if (node >= n) return;
  const uint4* Yv = (const uint4*)Y;   // 8 f16 per uint4, 16 per row

  float s0[8] = {0.f, 0.f, 0.f, 0.f, 0.f, 0.f, 0.f, 0.f};
  float s1[8] = {0.f, 0.f, 0.f, 0.f, 0.f, 0.f, 0.f, 0.f};
  auto up = [](uint4 v, float* a) {
    __half2* hp = (__half2*)&v;
    #pragma unroll
    for (int q = 0; q < 4; ++q) {
      float2 f = __half22float2(hp[q]);
      a[2 * q] += f.x;
      a[2 * q + 1] += f.y;
    }
  };
  up(Yv[(size_t)node * 16 + sl], s0);          // self term
  int e0 = rowptr[node], e1 = rowptr[node + 1];
  int e = e0;
  for (; e + 8 <= e1; e += 8) {
    int c0 = col[e],     c1 = col[e + 1], c2 = col[e + 2], c3 = col[e + 3];
    int c4 = col[e + 4], c5 = col[e + 5], c6 = col[e + 6], c7 = col[e + 7];
    uint4 v0 = Yv[(size_t)c0 * 16 + sl];
    uint4 v1 = Yv[(size_t)c1 * 16 + sl];
    uint4 v2 = Yv[(size_t)c2 * 16 + sl];
    uint4 v3 = Yv[(size_t)c3 * 16 + sl];
    uint4 v4 = Yv[(size_t)c4 * 16 + sl];
    uint4 v5 = Yv[(size_t)c5 * 16 + sl];
    uint4 v6 = Yv[(size_t)c6 * 16 + sl];
    uint4 v7 = Yv[(size_t)c7 * 16 + sl];
    up(v0, s0); up(v1, s1); up(v2, s0); up(v3, s1);
    up(v4, s0); up(v5, s1); up(v6, s0); up(v7, s1);
  }
  for (; e + 4 <= e1; e += 4) {
    int c0 = col[e], c1 = col[e + 1], c2 = col[e + 2], c3 = col[e + 3];
    uint4 v0 = Yv[(size_t)c0 * 16 + sl];
    uint4 v1 = Yv[(size_t)c1 * 16 + sl];
    uint4 v2 = Yv[(size_t)c2 * 16 + sl];
    uint4 v3 = Yv[(size_t)c3 * 16 + sl];
    up(v0, s0); up(v1, s1); up(v2, s0); up(v3, s1);
  }
  for (; e < e1; ++e) up(Yv[(size_t)col[e] * 16 + sl], s0);

  float nm = nrm[node];
  const float* bp = bias + sl * 8;
  __half h[8], l[8];
  #pragma unroll
  for (int q = 0; q < 8; ++q) {
    float o = fmaxf(fmaf(s0[q] + s1[q], nm, bp[q]), 0.f);
    h[q] = __float2half_rn(o);
    l[q] = __float2half_rn(o - __half2float(h[q]));
  }
  ((uint4*)Xh)[(size_t)node * 16 + sl] = *(uint4*)h;
  ((uint4*)Xl)[(size_t)node * 16 + sl] = *(uint4*)l;
}

extern "C" void kernel_launch(void* const* d_in, const int* in_sizes, int n_in,
                              void* d_out, int out_size, void* d_ws, size_t ws_size,
                              hipStream_t stream) {
  const float* x     = (const float*)d_in[0];
  const int*   ei    = (const int*)d_in[1];
  const float* convW = (const float*)d_in[2];
  const float* convB = (const float*)d_in[3];
  const float* w1    = (const float*)d_in[4];
  const float* b1    = (const float*)d_in[5];
  const float* w2    = (const float*)d_in[6];
  const float* b2    = (const float*)d_in[7];
  float* out = (float*)d_out;

  int N = in_sizes[0] / D;
  int E = in_sizes[1] / 2;
  int L = in_sizes[2] / (D * D);
  int NBKT = (N + 255) >> 8;

  char* ws = (char*)d_ws;
  size_t off = 0;
  auto alloc = [&](size_t bytes) -> char* {
    char* p = ws + off;
    off += (bytes + 255) & ~(size_t)255;
    return p;
  };
  float*  nrm    = (float*)alloc((size_t)N * 4);
  int*    rowptr = (int*)alloc((size_t)(N + 1) * 4);
  int*    col    = (int*)alloc((size_t)E * 4);
  int*    bcnt   = (int*)alloc(512 * 4);
  int*    boff   = (int*)alloc(512 * 4);
  int*    bcur   = (int*)alloc(512 * 4);
  uint2*  bed    = (uint2*)alloc((size_t)E * 8);
  __half* Xh     = (__half*)alloc((size_t)N * D * 2);
  __half* Xl     = (__half*)alloc((size_t)N * D * 2);
  __half* Yh     = (__half*)alloc((size_t)N * D * 2);
  __half* WcTh   = (__half*)alloc((size_t)L * D * D * 2);
  __half* WcTl   = (__half*)alloc((size_t)L * D * D * 2);
  __half* W1Th   = (__half*)alloc((size_t)D * FFN * 2);
  __half* W1Tl   = (__half*)alloc((size_t)D * FFN * 2);
  __half* W2Th   = (__half*)alloc((size_t)FFN * BOT * 2);
  __half* W2Tl   = (__half*)alloc((size_t)FFN * BOT * 2);

  // ---- CSR build (bucketed counting sort) ----
  int gS = (E + EPB - 1) / EPB;
  hipMemsetAsync(bcnt, 0, 512 * 4, stream);
  k_bcnt<<<gS, 256, 0, stream>>>(ei + E, bcnt, E);
  k_bscan<<<1, 256, 0, stream>>>(bcnt, boff, bcur, NBKT, E);
  k_bscatter<<<gS, 256, 0, stream>>>(ei, bcur, bed, E);
  k_bcsr<<<NBKT, 256, 0, stream>>>(bed, boff, rowptr, nrm, col, N, E);

  // ---- operand prep ----
  int n8 = N * D / 8;
  k_split<<<(n8 + 255) / 256, 256, 0, stream>>>(x, Xh, Xl, n8);
  k_splitwc<<<(L * D * D + 255) / 256, 256, 0, stream>>>(convW, WcTh, WcTl, L * D * D);
  k_splitw<<<(D * FFN + 255) / 256, 256, 0, stream>>>(w1, W1Th, W1Tl, D, FFN);
  k_splitw<<<(FFN * BOT + 255) / 256, 256, 0, stream>>>(w2, W2Th, W2Tl, FFN, BOT);

  // ---- GCN layers ----
  int nRB = (N + 63) / 64;
  for (int l = 0; l < L; ++l) {
    k_conv<<<nRB, 256, 0, stream>>>(
        Xh, Xl, WcTh + (size_t)l * D * D, WcTl + (size_t)l * D * D, nrm, Yh, N);
    k_agg<<<(N * 16 + 255) / 256, 256, 0, stream>>>(Yh, rowptr, col, nrm, convB + (size_t)l * D,
                                                    Xh, Xl, N);
  }

  // ---- fused MLP (BM=128) ----
  int nRB2 = (N + 127) / 128;
  k_mlp<<<nRB2, 256, 0, stream>>>(Xh, Xl, W1Th, W1Tl, b1, W2Th, W2Tl, b2, out, N);
}

// Round 18
// 254.627 us; speedup vs baseline: 1.0551x; 1.0551x over previous
//
#include <hip/hip_runtime.h>
#include <hip/hip_fp16.h>

#define D 128
#define FFN 512
#define BOT 64
#define EPB 4096      // edges per bucketing block

typedef _Float16 f16x8 __attribute__((ext_vector_type(8)));
typedef float f32x4 __attribute__((ext_vector_type(4)));

// ================ CSR build via bucketed counting sort ================

__global__ __launch_bounds__(256) void k_bcnt(const int* __restrict__ dst, int* __restrict__ bcnt, int nE) {
  __shared__ int h[256];
  int t = threadIdx.x;
  h[t] = 0;
  __syncthreads();
  int base = blockIdx.x * EPB;
  #pragma unroll
  for (int m = 0; m < EPB / 256; ++m) {
    int idx = base + m * 256 + t;
    if (idx < nE) atomicAdd(&h[dst[idx] >> 8], 1);
  }
  __syncthreads();
  if (h[t] > 0) atomicAdd(&bcnt[t], h[t]);
}

__global__ __launch_bounds__(256) void k_bscan(const int* __restrict__ bcnt, int* __restrict__ boff,
                                               int* __restrict__ bcur, int nbkt, int nE) {
  __shared__ int s[256];
  int t = threadIdx.x;
  int v = (t < nbkt) ? bcnt[t] : 0;
  s[t] = v;
  __syncthreads();
  for (int d = 1; d < 256; d <<= 1) {
    int add = (t >= d) ? s[t - d] : 0;
    __syncthreads();
    s[t] += add;
    __syncthreads();
  }
  int ex = s[t] - v;
  boff[t] = ex;
  bcur[t] = ex;
  if (t == 255) boff[256] = nE;
  if (t >= nbkt) boff[t] = nE;
}

__global__ __launch_bounds__(256) void k_bscatter(const int* __restrict__ ei, int* __restrict__ bcur,
                                                  uint2* __restrict__ bed, int nE) {
  __shared__ uint2 st[EPB];
  __shared__ int cnt[256], off[256], base[256], cur[256];
  int t = threadIdx.x;
  int blk0 = blockIdx.x * EPB;
  int nblk = nE - blk0;
  if (nblk > EPB) nblk = EPB;

  cnt[t] = 0;
  cur[t] = 0;
  __syncthreads();

  int rs[EPB / 256], rd[EPB / 256];
  #pragma unroll
  for (int m = 0; m < EPB / 256; ++m) {
    int idx = blk0 + m * 256 + t;
    if (idx < nE) {
      rs[m] = ei[idx];
      rd[m] = ei[nE + idx];
      atomicAdd(&cnt[rd[m] >> 8], 1);
    } else {
      rd[m] = -1;
    }
  }
  __syncthreads();

  int v = cnt[t];
  off[t] = v;
  __syncthreads();
  for (int d = 1; d < 256; d <<= 1) {
    int add = (t >= d) ? off[t - d] : 0;
    __syncthreads();
    off[t] += add;
    __syncthreads();
  }
  int ex = off[t] - v;
  __syncthreads();
  off[t] = ex;
  base[t] = (v > 0) ? atomicAdd(&bcur[t], v) : 0;
  __syncthreads();

  #pragma unroll
  for (int m = 0; m < EPB / 256; ++m) {
    if (rd[m] >= 0) {
      int b = rd[m] >> 8;
      int p = off[b] + atomicAdd(&cur[b], 1);
      st[p] = make_uint2((unsigned)rs[m], (unsigned)rd[m]);
    }
  }
  __syncthreads();

  for (int j = t; j < nblk; j += 256) {
    uint2 pr = st[j];
    int b = (int)(pr.y >> 8);
    bed[base[b] + (j - off[b])] = pr;
  }
}

__global__ __launch_bounds__(256) void k_bcsr(const uint2* __restrict__ bed, const int* __restrict__ boff,
                                              int* __restrict__ rowptr, float* __restrict__ nrm,
                                              int* __restrict__ col, int N, int nE) {
  __shared__ int cnt[256], noff[256], cur[256];
  int t = threadIdx.x;
  int b = blockIdx.x;
  int e0 = boff[b], e1 = boff[b + 1];

  cnt[t] = 0;
  __syncthreads();
  for (int j = e0 + t; j < e1; j += 256)
    atomicAdd(&cnt[bed[j].y & 255], 1);
  __syncthreads();

  int v = cnt[t];
  noff[t] = v;
  __syncthreads();
  for (int d = 1; d < 256; d <<= 1) {
    int add = (t >= d) ? noff[t - d] : 0;
    __syncthreads();
    noff[t] += add;
    __syncthreads();
  }
  int ex = noff[t] - v;
  __syncthreads();
  noff[t] = ex;
  cur[t] = ex;
  __syncthreads();

  int node = (b << 8) + t;
  if (node < N) {
    rowptr[node] = e0 + ex;
    nrm[node] = rsqrtf((float)v + 1.0f);
  }
  if (b == 0 && t == 0) rowptr[N] = nE;

  for (int j = e0 + t; j < e1; j += 256) {
    uint2 pr = bed[j];
    int d2 = (int)(pr.y & 255);
    int p = atomicAdd(&cur[d2], 1);
    col[e0 + p] = (int)pr.x;
  }
}

// ---------------- split helpers ----------------

__global__ __launch_bounds__(256) void k_split(const float* __restrict__ X,
                                               __half* __restrict__ Xh, __half* __restrict__ Xl, int n8) {
  int i = blockIdx.x * 256 + threadIdx.x;
  if (i >= n8) return;
  float4 a = ((const float4*)X)[i * 2];
  float4 b = ((const float4*)X)[i * 2 + 1];
  float v[8] = {a.x, a.y, a.z, a.w, b.x, b.y, b.z, b.w};
  __half2 hh[4], ll[4];
  #pragma unroll
  for (int q = 0; q < 4; ++q) {
    __half h0 = __float2half_rn(v[2 * q]);
    __half h1 = __float2half_rn(v[2 * q + 1]);
    __half l0 = __float2half_rn(v[2 * q] - __half2float(h0));
    __half l1 = __float2half_rn(v[2 * q + 1] - __half2float(h1));
    hh[q] = __halves2half2(h0, h1);
    ll[q] = __halves2half2(l0, l1);
  }
  *(uint4*)(Xh + (size_t)i * 8) = *(uint4*)hh;
  *(uint4*)(Xl + (size_t)i * 8) = *(uint4*)ll;
}

// merged weight prep: conv (L x DxD) + w1 (D x FFN) + w2 (FFN x BOT),
// all split+transposed. Region-dispatched flat id.
__global__ __launch_bounds__(256) void k_prepw(const float* __restrict__ convW,
                                               const float* __restrict__ w1,
                                               const float* __restrict__ w2,
                                               __half* __restrict__ WcTh, __half* __restrict__ WcTl,
                                               __half* __restrict__ W1Th, __half* __restrict__ W1Tl,
                                               __half* __restrict__ W2Th, __half* __restrict__ W2Tl,
                                               int nConv) {
  int id = blockIdx.x * 256 + threadIdx.x;
  float v;
  __half* dh;
  __half* dl;
  int idx;
  if (id < nConv) {
    int l = id / (D * D), r = id % (D * D);
    int n = r / D, k = r % D;
    v = convW[(size_t)l * D * D + (size_t)k * D + n];
    dh = WcTh; dl = WcTl; idx = id;
  } else if (id < nConv + D * FFN) {
    idx = id - nConv;
    int n = idx / D, k = idx % D;
    v = w1[(size_t)k * FFN + n];
    dh = W1Th; dl = W1Tl;
  } else if (id < nConv + D * FFN + FFN * BOT) {
    idx = id - nConv - D * FFN;
    int n = idx / FFN, k = idx % FFN;
    v = w2[(size_t)k * BOT + n];
    dh = W2Th; dl = W2Tl;
  } else {
    return;
  }
  __half h = __float2half_rn(v);
  dh[idx] = h;
  dl[idx] = __float2half_rn(v - __half2float(h));
}

// ---------------- conv GEMM v3: Y = (X @ W) * nrm[row] ----------------
// X fragments (h+l) gathered ONCE into registers; full W (h+l) staged into
// LDS once (69.6 KB, coalesced); ONE barrier. 4 waves: 2m x 2n; tile 32 x 64.

__global__ __launch_bounds__(256, 2)
void k_conv(const __half* __restrict__ Xh_g, const __half* __restrict__ Xl_g,
            const __half* __restrict__ WhT, const __half* __restrict__ WlT,
            const float* __restrict__ aux, __half* __restrict__ Yo, int M) {
  __shared__ __half Bhs[128][136], Bls[128][136];

  const int t = threadIdx.x;
  const int rbase = blockIdx.x * 64;
  const int lane = t & 63, wid = t >> 6;
  const int wr = (wid >> 1) * 32;
  const int wc = (wid & 1) * 64;
  const int lr = lane & 15, lq = lane >> 4;

  // stage whole W (128 cols x 128 k), h+l
  #pragma unroll
  for (int mm = 0; mm < 8; ++mm) {
    int idx = mm * 256 + t;
    int c = idx >> 4, q = idx & 15;
    size_t src = (size_t)c * D + q * 8;
    *(uint4*)&Bhs[c][q * 8] = *(const uint4*)(WhT + src);
    *(uint4*)&Bls[c][q * 8] = *(const uint4*)(WlT + src);
  }

  // gather X fragments into registers (one time)
  f16x8 fa[2][4], fal[2][4];
  #pragma unroll
  for (int m = 0; m < 2; ++m) {
    int row = rbase + wr + m * 16 + lr;
    bool ok = row < M;
    #pragma unroll
    for (int kf = 0; kf < 4; ++kf) {
      uint4 vh = {0, 0, 0, 0}, vl = {0, 0, 0, 0};
      if (ok) {
        vh = *(const uint4*)(Xh_g + (size_t)row * D + kf * 32 + lq * 8);
        vl = *(const uint4*)(Xl_g + (size_t)row * D + kf * 32 + lq * 8);
      }
      fa[m][kf] = *(f16x8*)&vh;
      fal[m][kf] = *(f16x8*)&vl;
    }
  }
  __syncthreads();

  f32x4 acc[2][4];
  #pragma unroll
  for (int m = 0; m < 2; ++m)
    #pragma unroll
    for (int n = 0; n < 4; ++n) acc[m][n] = (f32x4){0.f, 0.f, 0.f, 0.f};

  #pragma unroll
  for (int kf = 0; kf < 4; ++kf) {
    f16x8 fb[4], fbl[4];
    #pragma unroll
    for (int n = 0; n < 4; ++n) {
      fb[n]  = *(const f16x8*)&Bhs[wc + n * 16 + lr][kf * 32 + lq * 8];
      fbl[n] = *(const f16x8*)&Bls[wc + n * 16 + lr][kf * 32 + lq * 8];
    }
    #pragma unroll
    for (int m = 0; m < 2; ++m)
      #pragma unroll
      for (int n = 0; n < 4; ++n) {
        acc[m][n] = __builtin_amdgcn_mfma_f32_16x16x32_f16(fa[m][kf], fb[n], acc[m][n], 0, 0, 0);
        acc[m][n] = __builtin_amdgcn_mfma_f32_16x16x32_f16(fa[m][kf], fbl[n], acc[m][n], 0, 0, 0);
        acc[m][n] = __builtin_amdgcn_mfma_f32_16x16x32_f16(fal[m][kf], fb[n], acc[m][n], 0, 0, 0);
      }
  }

  #pragma unroll
  for (int m = 0; m < 2; ++m)
    #pragma unroll
    for (int j = 0; j < 4; ++j) {
      int row = rbase + wr + m * 16 + lq * 4 + j;
      if (row < M) {
        float s = aux[row];
        #pragma unroll
        for (int n = 0; n < 4; ++n) {
          int colg = wc + n * 16 + lr;
          Yo[(size_t)row * D + colg] = __float2half_rn(acc[m][n][j] * s);
        }
      }
    }
}

// ---------------- fused MLP v2 (best measured): Out = relu(X@W1+b1)@W2 + b2 ----------------
// 64-row blocks. X staged once (full K=128). Per 64-wide FFN chunk:
//   stage W1-chunk -> 48 barrier-free MFMAs (fc1) -> Hs -> stage W2-chunk into
//   the SAME buffer -> 16 MFMAs (fc2, accumulate Out in regs).
// LDS = 78.8 KB -> 2 blocks/CU. VGPR 88, no spill.

__global__ __launch_bounds__(256, 2)
void k_mlp(const __half* __restrict__ Xh_g, const __half* __restrict__ Xl_g,
           const __half* __restrict__ W1hT, const __half* __restrict__ W1lT,
           const float* __restrict__ B1,
           const __half* __restrict__ W2hT, const __half* __restrict__ W2lT,
           const float* __restrict__ B2,
           float* __restrict__ Out, int M) {
  __shared__ __half Xhs[64][136], Xls[64][136];
  __shared__ __half Ws[2][64][136];     // W1 h/l chunk; reused for W2 h/l
  __shared__ __half Hs[64][72];

  const int t = threadIdx.x;
  const int rbase = blockIdx.x * 64;
  const int lane = t & 63, wid = t >> 6;
  const int wr = (wid >> 1) * 32;
  const int wcn = (wid & 1) * 32;
  const int lr = lane & 15, lq = lane >> 4;

  // stage X once, full K
  #pragma unroll
  for (int mm = 0; mm < 4; ++mm) {
    int idx = mm * 256 + t;
    int row = idx >> 4, q = idx & 15;
    int gr = rbase + row;
    uint4 vh = {0, 0, 0, 0}, vl = {0, 0, 0, 0};
    if (gr < M) {
      vh = *(const uint4*)(Xh_g + (size_t)gr * D + q * 8);
      vl = *(const uint4*)(Xl_g + (size_t)gr * D + q * 8);
    }
    *(uint4*)&Xhs[row][q * 8] = vh;
    *(uint4*)&Xls[row][q * 8] = vl;
  }

  f32x4 accO[2][2];
  #pragma unroll
  for (int m = 0; m < 2; ++m)
    #pragma unroll
    for (int n = 0; n < 2; ++n) accO[m][n] = (f32x4){0.f, 0.f, 0.f, 0.f};

  for (int ch = 0; ch < FFN / 64; ++ch) {
    __syncthreads();   // (a) prior fc2 done with Ws/Hs; first iter: X visible
    // stage W1 chunk: 64 ffn-cols x 128 k
    #pragma unroll
    for (int mm = 0; mm < 4; ++mm) {
      int idx = mm * 256 + t;
      int c = idx >> 4, q = idx & 15;
      size_t src = (size_t)(ch * 64 + c) * D + q * 8;
      *(uint4*)&Ws[0][c][q * 8] = *(const uint4*)(W1hT + src);
      *(uint4*)&Ws[1][c][q * 8] = *(const uint4*)(W1lT + src);
    }
    __syncthreads();   // (b) W1 ready

    // ---- fc1: 48 MFMAs, no barrier ----
    f32x4 accH[2][2];
    #pragma unroll
    for (int m = 0; m < 2; ++m)
      #pragma unroll
      for (int n = 0; n < 2; ++n) accH[m][n] = (f32x4){0.f, 0.f, 0.f, 0.f};

    #pragma unroll
    for (int kf = 0; kf < 4; ++kf) {
      f16x8 fa[2], fal[2], fb[2], fbl[2];
      #pragma unroll
      for (int m = 0; m < 2; ++m) {
        fa[m]  = *(const f16x8*)&Xhs[wr + m * 16 + lr][kf * 32 + lq * 8];
        fal[m] = *(const f16x8*)&Xls[wr + m * 16 + lr][kf * 32 + lq * 8];
      }
      #pragma unroll
      for (int n = 0; n < 2; ++n) {
        fb[n]  = *(const f16x8*)&Ws[0][wcn + n * 16 + lr][kf * 32 + lq * 8];
        fbl[n] = *(const f16x8*)&Ws[1][wcn + n * 16 + lr][kf * 32 + lq * 8];
      }
      #pragma unroll
      for (int m = 0; m < 2; ++m)
        #pragma unroll
        for (int n = 0; n < 2; ++n) {
          accH[m][n] = __builtin_amdgcn_mfma_f32_16x16x32_f16(fa[m], fb[n], accH[m][n], 0, 0, 0);
          accH[m][n] = __builtin_amdgcn_mfma_f32_16x16x32_f16(fa[m], fbl[n], accH[m][n], 0, 0, 0);
          accH[m][n] = __builtin_amdgcn_mfma_f32_16x16x32_f16(fal[m], fb[n], accH[m][n], 0, 0, 0);
        }
    }

    // relu + b1 -> Hs
    {
      float bb1[2];
      #pragma unroll
      for (int n = 0; n < 2; ++n) bb1[n] = B1[ch * 64 + wcn + n * 16 + lr];
      #pragma unroll
      for (int m = 0; m < 2; ++m)
        #pragma unroll
        for (int n = 0; n < 2; ++n)
          #pragma unroll
          for (int j = 0; j < 4; ++j) {
            int rl = wr + m * 16 + lq * 4 + j;
            int cl = wcn + n * 16 + lr;
            Hs[rl][cl] = __float2half_rn(fmaxf(accH[m][n][j] + bb1[n], 0.f));
          }
    }
    __syncthreads();   // (c) Hs ready; fc1 done reading Ws
    // stage W2 chunk: 64 bot-cols x 64 k into same Ws region
    #pragma unroll
    for (int mm = 0; mm < 2; ++mm) {
      int idx = mm * 256 + t;
      int c = idx >> 3, q = idx & 7;
      size_t src = (size_t)c * FFN + ch * 64 + q * 8;
      *(uint4*)&Ws[0][c][q * 8] = *(const uint4*)(W2hT + src);
      *(uint4*)&Ws[1][c][q * 8] = *(const uint4*)(W2lT + src);
    }
    __syncthreads();   // (d) W2 ready

    // ---- fc2: 16 MFMAs ----
    #pragma unroll
    for (int s = 0; s < 2; ++s) {
      f16x8 fha[2], fwb[2], fwbl[2];
      #pragma unroll
      for (int m = 0; m < 2; ++m)
        fha[m] = *(const f16x8*)&Hs[wr + m * 16 + lr][s * 32 + lq * 8];
      #pragma unroll
      for (int n = 0; n < 2; ++n) {
        fwb[n]  = *(const f16x8*)&Ws[0][wcn + n * 16 + lr][s * 32 + lq * 8];
        fwbl[n] = *(const f16x8*)&Ws[1][wcn + n * 16 + lr][s * 32 + lq * 8];
      }
      #pragma unroll
      for (int m = 0; m < 2; ++m)
        #pragma unroll
        for (int n = 0; n < 2; ++n) {
          accO[m][n] = __builtin_amdgcn_mfma_f32_16x16x32_f16(fha[m], fwb[n], accO[m][n], 0, 0, 0);
          accO[m][n] = __builtin_amdgcn_mfma_f32_16x16x32_f16(fha[m], fwbl[n], accO[m][n], 0, 0, 0);
        }
    }
  }

  // epilogue: Out += b2
  #pragma unroll
  for (int m = 0; m < 2; ++m)
    #pragma unroll
    for (int j = 0; j < 4; ++j) {
      int row = rbase + wr + m * 16 + lq * 4 + j;
      if (row < M) {
        #pragma unroll
        for (int n = 0; n < 2; ++n) {
          int colg = wcn + n * 16 + lr;
          Out[(size_t)row * BOT + colg] = accO[m][n][j] + B2[colg];
        }
      }
    }
}

// ---------------- aggregate: X' = relu(norm[i]*(y_i + sum y_src) + b), split output ----------------
// 16-lane sub-groups: 1 node per 16 lanes, 16B (8ch) per lane. 4-deep unroll (r13 best).

__global__ __launch_bounds__(256) void k_agg(const __half* __restrict__ Y,
                                             const int* __restrict__ rowptr, const int* __restrict__ col,
                                             const float* __restrict__ nrm, const float* __restrict__ bias,
                                             __half* __restrict__ Xh, __half* __restrict__ Xl, int n) {
  int gtid = blockIdx.x * 256 + threadIdx.x;
  int node = gtid >> 4;
  int sl = threadIdx.x & 15;
  if (node >= n) return;
  const uint4* Yv = (const uint4*)Y;   // 8 f16 per uint4, 16 per row

  float s0[8] = {0.f, 0.f, 0.f, 0.f, 0.f, 0.f, 0.f, 0.f};
  float s1[8] = {0.f, 0.f, 0.f, 0.f, 0.f, 0.f, 0.f, 0.f};
  auto up = [](uint4 v, float* a) {
    __half2* hp = (__half2*)&v;
    #pragma unroll
    for (int q = 0; q < 4; ++q) {
      float2 f = __half22float2(hp[q]);
      a[2 * q] += f.x;
      a[2 * q + 1] += f.y;
    }
  };
  up(Yv[(size_t)node * 16 + sl], s0);          // self term
  int e0 = rowptr[node], e1 = rowptr[node + 1];
  int e = e0;
  for (; e + 4 <= e1; e += 4) {
    int c0 = col[e], c1 = col[e + 1], c2 = col[e + 2], c3 = col[e + 3];
    uint4 v0 = Yv[(size_t)c0 * 16 + sl];
    uint4 v1 = Yv[(size_t)c1 * 16 + sl];
    uint4 v2 = Yv[(size_t)c2 * 16 + sl];
    uint4 v3 = Yv[(size_t)c3 * 16 + sl];
    up(v0, s0); up(v1, s1); up(v2, s0); up(v3, s1);
  }
  for (; e < e1; ++e) up(Yv[(size_t)col[e] * 16 + sl], s0);

  float nm = nrm[node];
  const float* bp = bias + sl * 8;
  __half h[8], l[8];
  #pragma unroll
  for (int q = 0; q < 8; ++q) {
    float o = fmaxf(fmaf(s0[q] + s1[q], nm, bp[q]), 0.f);
    h[q] = __float2half_rn(o);
    l[q] = __float2half_rn(o - __half2float(h[q]));
  }
  ((uint4*)Xh)[(size_t)node * 16 + sl] = *(uint4*)h;
  ((uint4*)Xl)[(size_t)node * 16 + sl] = *(uint4*)l;
}

extern "C" void kernel_launch(void* const* d_in, const int* in_sizes, int n_in,
                              void* d_out, int out_size, void* d_ws, size_t ws_size,
                              hipStream_t stream) {
  const float* x     = (const float*)d_in[0];
  const int*   ei    = (const int*)d_in[1];
  const float* convW = (const float*)d_in[2];
  const float* convB = (const float*)d_in[3];
  const float* w1    = (const float*)d_in[4];
  const float* b1    = (const float*)d_in[5];
  const float* w2    = (const float*)d_in[6];
  const float* b2    = (const float*)d_in[7];
  float* out = (float*)d_out;

  int N = in_sizes[0] / D;
  int E = in_sizes[1] / 2;
  int L = in_sizes[2] / (D * D);
  int NBKT = (N + 255) >> 8;

  char* ws = (char*)d_ws;
  size_t off = 0;
  auto alloc = [&](size_t bytes) -> char* {
    char* p = ws + off;
    off += (bytes + 255) & ~(size_t)255;
    return p;
  };
  float*  nrm    = (float*)alloc((size_t)N * 4);
  int*    rowptr = (int*)alloc((size_t)(N + 1) * 4);
  int*    col    = (int*)alloc((size_t)E * 4);
  int*    bcnt   = (int*)alloc(512 * 4);
  int*    boff   = (int*)alloc(512 * 4);
  int*    bcur   = (int*)alloc(512 * 4);
  uint2*  bed    = (uint2*)alloc((size_t)E * 8);
  __half* Xh     = (__half*)alloc((size_t)N * D * 2);
  __half* Xl     = (__half*)alloc((size_t)N * D * 2);
  __half* Yh     = (__half*)alloc((size_t)N * D * 2);
  __half* WcTh   = (__half*)alloc((size_t)L * D * D * 2);
  __half* WcTl   = (__half*)alloc((size_t)L * D * D * 2);
  __half* W1Th   = (__half*)alloc((size_t)D * FFN * 2);
  __half* W1Tl   = (__half*)alloc((size_t)D * FFN * 2);
  __half* W2Th   = (__half*)alloc((size_t)FFN * BOT * 2);
  __half* W2Tl   = (__half*)alloc((size_t)FFN * BOT * 2);

  // ---- CSR build (bucketed counting sort) ----
  int gS = (E + EPB - 1) / EPB;
  hipMemsetAsync(bcnt, 0, 512 * 4, stream);
  k_bcnt<<<gS, 256, 0, stream>>>(ei + E, bcnt, E);
  k_bscan<<<1, 256, 0, stream>>>(bcnt, boff, bcur, NBKT, E);
  k_bscatter<<<gS, 256, 0, stream>>>(ei, bcur, bed, E);
  k_bcsr<<<NBKT, 256, 0, stream>>>(bed, boff, rowptr, nrm, col, N, E);

  // ---- operand prep ----
  int n8 = N * D / 8;
  k_split<<<(n8 + 255) / 256, 256, 0, stream>>>(x, Xh, Xl, n8);
  int nConv = L * D * D;
  int totalW = nConv + D * FFN + FFN * BOT;
  k_prepw<<<(totalW + 255) / 256, 256, 0, stream>>>(convW, w1, w2,
                                                    WcTh, WcTl, W1Th, W1Tl, W2Th, W2Tl, nConv);

  // ---- GCN layers ----
  int nRB = (N + 63) / 64;
  for (int l = 0; l < L; ++l) {
    k_conv<<<nRB, 256, 0, stream>>>(
        Xh, Xl, WcTh + (size_t)l * D * D, WcTl + (size_t)l * D * D, nrm, Yh, N);
    k_agg<<<(N * 16 + 255) / 256, 256, 0, stream>>>(Yh, rowptr, col, nrm, convB + (size_t)l * D,
                                                    Xh, Xl, N);
  }

  // ---- fused MLP ----
  k_mlp<<<nRB, 256, 0, stream>>>(Xh, Xl, W1Th, W1Tl, b1, W2Th, W2Tl, b2, out, N);
}